// Round 12
// baseline (151.174 us; speedup 1.0000x reference)
//
#include <hip/hip_runtime.h>
#include <hip/hip_bf16.h>
#include <stdint.h>

#define B_DIM 128
#define N_DIM 16384
#define E_DIM 1048576
#define H_DIM 512
#define C_DIM 10
#define NWG 256               // wgs for hist/place
#define CHUNK (E_DIM / NWG)   // 4096 edges per wg
#define NWORD (N_DIM / 2)     // 8192 packed uint words (2 bins each)
#define NGRP 8                // scan groups
#define WPG (NWG / NGRP)      // 32 wgs per group
#define NSLICE 2              // bf16 diffusion column slices (64 cols = 2 MB each)
#define SPLITK 64
#define KC (N_DIM / SPLITK)   // 256

typedef __attribute__((ext_vector_type(8))) short short8;   // 8 bf16 = 4 VGPRs
typedef __attribute__((ext_vector_type(4))) float f32x4;    // MFMA accumulator

// float -> bf16 round-to-nearest-even (finite inputs)
__device__ __forceinline__ uint32_t f2bf(float f) {
    uint32_t u = __float_as_uint(f);
    return (u + 0x7fffu + ((u >> 16) & 1u)) >> 16;
}

// ---------- transpose x (B,N) f32 -> xTh (N,B) bf16 (no scaling) ----------
__global__ void k_transpose(const float* __restrict__ x, uint16_t* __restrict__ xTh) {
    __shared__ float tile[32][33];
    int bx = blockIdx.x, by = blockIdx.y;
    int tx = threadIdx.x, ty = threadIdx.y;
    int n = bx * 32 + tx, b = by * 32 + ty;
    tile[ty][tx] = x[(size_t)b * N_DIM + n];
    __syncthreads();
    int n2 = bx * 32 + ty, b2 = by * 32 + tx;
    xTh[(size_t)n2 * B_DIM + b2] = (uint16_t)f2bf(tile[tx][ty]);
}

// ---------- per-wg LDS histogram of dst (2x16-bit packed), flush to slab ----------
__global__ void __launch_bounds__(256) k_hist1(const int* __restrict__ dst,
                                               uint32_t* __restrict__ slab) {
    __shared__ uint32_t lh[NWORD];   // 32 KB
    int w = blockIdx.x, t = threadIdx.x;
#pragma unroll
    for (int i = 0; i < NWORD / 256; i++) lh[i * 256 + t] = 0;
    __syncthreads();
#pragma unroll
    for (int i = 0; i < CHUNK / 256; i++) {
        int d = dst[w * CHUNK + i * 256 + t];
        atomicAdd(&lh[d >> 1], 1u << ((d & 1) << 4));
    }
    __syncthreads();
#pragma unroll
    for (int i = 0; i < NWORD / 256; i++)
        slab[(size_t)w * NWORD + i * 256 + t] = lh[i * 256 + t];
}

// ---------- within-group (32 wgs) in-place exclusive prefix; per-group totals ----------
__global__ void __launch_bounds__(256) k_scanA(uint32_t* __restrict__ slab,
                                               uint32_t* __restrict__ grp) {
    int b = blockIdx.x;                 // 0..255
    int g = b >> 5;                     // group 0..7
    int j = (b & 31) * 256 + threadIdx.x;  // word 0..8191
    uint32_t lo = 0, hi = 0;
    for (int w = g * WPG; w < (g + 1) * WPG; w++) {
        uint32_t c = slab[(size_t)w * NWORD + j];
        slab[(size_t)w * NWORD + j] = lo | (hi << 16);
        lo += c & 0xffffu;
        hi += c >> 16;
    }
    grp[(size_t)g * NWORD + j] = lo | (hi << 16);
}

// ---------- fused: cross-group exclusive prefix + global bin scan -> CSR offs ----------
__global__ void __launch_bounds__(1024) k_scanBC(uint32_t* __restrict__ grp,
                                                 int* __restrict__ offs) {
    __shared__ uint32_t part[1024];
    int t = threadIdx.x;
    uint32_t loc[16];
    uint32_t s = 0;
    int wbase = t * 8;
#pragma unroll
    for (int i = 0; i < 8; i++) {
        int j = wbase + i;
        uint32_t lo = 0, hi = 0;
#pragma unroll
        for (int g = 0; g < NGRP; g++) {
            uint32_t c = grp[(size_t)g * NWORD + j];
            grp[(size_t)g * NWORD + j] = lo | (hi << 16);
            lo += c & 0xffffu;
            hi += c >> 16;
        }
        loc[2 * i] = s;     s += lo;
        loc[2 * i + 1] = s; s += hi;
    }
    part[t] = s;
    __syncthreads();
    for (int off = 1; off < 1024; off <<= 1) {
        uint32_t v = (t >= off) ? part[t - off] : 0;
        __syncthreads();
        part[t] += v;
        __syncthreads();
    }
    uint32_t ex = (t == 0) ? 0 : part[t - 1];
#pragma unroll
    for (int i = 0; i < 16; i++) offs[t * 16 + i] = (int)(ex + loc[i]);
    if (t == 1023) offs[N_DIM] = (int)part[1023];
}

// ---------- atomic-free (global) placement: LDS cursor per wg ----------
__global__ void __launch_bounds__(256) k_place2(const int* __restrict__ src,
                                                const int* __restrict__ dst,
                                                const float* __restrict__ ew,
                                                const uint32_t* __restrict__ slab,
                                                const uint32_t* __restrict__ grp,
                                                const int* __restrict__ offs,
                                                int2* __restrict__ packed) {
    __shared__ uint32_t cur[N_DIM];   // 64 KB
    int w = blockIdx.x, t = threadIdx.x;
    int g = w >> 5;
#pragma unroll
    for (int i = 0; i < NWORD / 256; i++) {
        int j = i * 256 + t;
        uint32_t pv = slab[(size_t)w * NWORD + j];
        uint32_t gv = grp[(size_t)g * NWORD + j];
        int2 o = *(const int2*)&offs[2 * j];
        cur[2 * j]     = (uint32_t)o.x + (gv & 0xffffu) + (pv & 0xffffu);
        cur[2 * j + 1] = (uint32_t)o.y + (gv >> 16) + (pv >> 16);
    }
    __syncthreads();
#pragma unroll
    for (int i = 0; i < CHUNK / 256; i++) {
        int e = w * CHUNK + i * 256 + t;
        int s = src[e], d = dst[e];
        uint32_t pos = atomicAdd(&cur[d], 1u);   // LDS atomic
        packed[pos] = make_int2(s, __float_as_int(ew[e]));
    }
}

// ---------- weighted in-degree from sorted segments -> dinv (raw w in packed) ----------
__global__ void __launch_bounds__(256) k_deg(const int* __restrict__ offs,
                                             const int2* __restrict__ packed,
                                             float* __restrict__ dinv) {
    int d = blockIdx.x * 4 + (threadIdx.x >> 6);
    int lane = threadIdx.x & 63;
    int e0 = offs[d], e1 = offs[d + 1];
    float s = 0.f;
    for (int e = e0 + lane; e < e1; e += 64)
        s += __int_as_float(packed[e].y);
#pragma unroll
    for (int o = 32; o > 0; o >>= 1) s += __shfl_down(s, o);
    if (lane == 0) dinv[d] = rsqrtf(s + 1.0f);   // + self-loop weight 1; always > 0
}

// ---------- diffusion: bf16 gathers (unscaled table), XCD-pinned half-slices ----------
// grid = N_DIM/2 blocks x 256 thr (4 waves = 4 nodes); slice = bid&1 pins each XCD
// to a 2 MB bf16 column slice. Per 64-edge tile: ONE coalesced packed load
// (prefetched a tile early) with dinv[src] folded in-register at staging (64 KB
// dinv table, L2-hot, hidden under prefetch slack), then 8 unrolled
// {shfl-broadcast, 1KB uint4 gather, unpack, fma} steps, f32 accum.
// OOB lanes stage w=0 -> inert. packed in memory is never modified.
__global__ void __launch_bounds__(256) k_diffuse(const uint16_t* __restrict__ xTh,
                                                 const int* __restrict__ offs,
                                                 const int2* __restrict__ packed,
                                                 const float* __restrict__ dinv,
                                                 float* __restrict__ hT) {
    int bid = blockIdx.x;
    int slice = bid & (NSLICE - 1);
    int d = (bid >> 1) * 4 + (threadIdx.x >> 6);
    int lane = threadIdx.x & 63;
    int g = lane >> 3;                  // edge subgroup 0..7
    int colh = slice * 8 + (lane & 7);  // uint4 chunk within row (16 per row)
    const uint4* x4 = (const uint4*)xTh;
    float acc[8];
#pragma unroll
    for (int k = 0; k < 8; k++) acc[k] = 0.f;
    int e0 = offs[d], e1 = offs[d + 1];
    int el = e0 + lane;
    int2 p = (el < e1) ? packed[el] : make_int2(0, 0);
    p.y = __float_as_int(__int_as_float(p.y) * dinv[p.x]);   // w*dinv[src]; 0 stays 0
    for (int base = e0; base < e1; base += 64) {
        int2 pc = p;
        int en = base + 64 + lane;
        p = (en < e1) ? packed[en] : make_int2(0, 0);        // prefetch next tile
        p.y = __float_as_int(__int_as_float(p.y) * dinv[p.x]);
#pragma unroll
        for (int i = 0; i < 64; i += 8) {
            int idx = i + g;
            int sx = __shfl(pc.x, idx);
            float nm = __shfl(__int_as_float(pc.y), idx);
            uint4 xs = x4[(size_t)sx * 16 + colh];
            acc[0] = fmaf(nm, __uint_as_float(xs.x << 16), acc[0]);
            acc[1] = fmaf(nm, __uint_as_float(xs.x & 0xffff0000u), acc[1]);
            acc[2] = fmaf(nm, __uint_as_float(xs.y << 16), acc[2]);
            acc[3] = fmaf(nm, __uint_as_float(xs.y & 0xffff0000u), acc[3]);
            acc[4] = fmaf(nm, __uint_as_float(xs.z << 16), acc[4]);
            acc[5] = fmaf(nm, __uint_as_float(xs.z & 0xffff0000u), acc[5]);
            acc[6] = fmaf(nm, __uint_as_float(xs.w << 16), acc[6]);
            acc[7] = fmaf(nm, __uint_as_float(xs.w & 0xffff0000u), acc[7]);
        }
    }
#pragma unroll
    for (int off = 8; off <= 32; off <<= 1)
#pragma unroll
        for (int k = 0; k < 8; k++) acc[k] += __shfl_xor(acc[k], off);
    if (lane < 8) {
        float dv = dinv[d];
        uint4 sv = x4[(size_t)d * 16 + colh];   // self row (unscaled)
        float sf[8];
        sf[0] = __uint_as_float(sv.x << 16); sf[1] = __uint_as_float(sv.x & 0xffff0000u);
        sf[2] = __uint_as_float(sv.y << 16); sf[3] = __uint_as_float(sv.y & 0xffff0000u);
        sf[4] = __uint_as_float(sv.z << 16); sf[5] = __uint_as_float(sv.z & 0xffff0000u);
        sf[6] = __uint_as_float(sv.w << 16); sf[7] = __uint_as_float(sv.w & 0xffff0000u);
        int c = slice * 8 + lane;               // f32 col chunk (8 cols)
        float* hp = &hT[(size_t)d * B_DIM + c * 8];
        float4 o0, o1;
        o0.x = (acc[0] + dv * sf[0]) * dv; o0.y = (acc[1] + dv * sf[1]) * dv;
        o0.z = (acc[2] + dv * sf[2]) * dv; o0.w = (acc[3] + dv * sf[3]) * dv;
        o1.x = (acc[4] + dv * sf[4]) * dv; o1.y = (acc[5] + dv * sf[5]) * dv;
        o1.z = (acc[6] + dv * sf[6]) * dv; o1.w = (acc[7] + dv * sf[7]) * dv;
        *(float4*)hp = o0;
        *(float4*)(hp + 4) = o1;
    }
}

// ---------- hT f32 [n][b] -> hB bf16 [b][n] (transpose + convert) ----------
__global__ void k_h2b(const float* __restrict__ hT, uint16_t* __restrict__ hB) {
    __shared__ float tile[32][33];
    int n0 = blockIdx.x * 32, b0 = blockIdx.y * 32;
    int tx = threadIdx.x, ty = threadIdx.y;
    tile[ty][tx] = hT[(size_t)(n0 + ty) * B_DIM + b0 + tx];
    __syncthreads();
    hB[(size_t)(b0 + ty) * N_DIM + n0 + tx] = (uint16_t)f2bf(tile[tx][ty]);
}

// ---------- GEMM1 (MFMA bf16, error-compensated W): W1 x h -> split-K partials ----
__global__ void __launch_bounds__(256) k_gemm1(const float* __restrict__ W1,
                                               const uint16_t* __restrict__ hB,
                                               float* __restrict__ part) {
    int kc = blockIdx.x;               // 0..SPLITK-1
    int mt = blockIdx.y;               // 0..7
    int t = threadIdx.x, w = t >> 6, l = t & 63;
    int lr = l & 15;
    int lk = (l >> 4) * 8;
    int row = mt * 64 + w * 16 + lr;   // W1 row for A-frag
    int k0 = kc * KC;
    f32x4 acc[8] = {};
    const float* wbase = W1 + (size_t)row * N_DIM + k0 + lk;
    const uint16_t* hbase = hB + k0 + lk;
#pragma unroll 2
    for (int ks = 0; ks < KC; ks += 32) {
        float4 wa = *(const float4*)(wbase + ks);
        float4 wb = *(const float4*)(wbase + ks + 4);
        short8 bf[8];
#pragma unroll
        for (int c = 0; c < 8; c++)
            bf[c] = *(const short8*)(hbase + (size_t)(c * 16 + lr) * N_DIM + ks);
        float wv0 = wa.x, wv1 = wa.y, wv2 = wa.z, wv3 = wa.w;
        float wv4 = wb.x, wv5 = wb.y, wv6 = wb.z, wv7 = wb.w;
        short8 ahi, alo;
        uint32_t h0;
        h0 = f2bf(wv0); ahi[0] = (short)h0; alo[0] = (short)f2bf(wv0 - __uint_as_float(h0 << 16));
        h0 = f2bf(wv1); ahi[1] = (short)h0; alo[1] = (short)f2bf(wv1 - __uint_as_float(h0 << 16));
        h0 = f2bf(wv2); ahi[2] = (short)h0; alo[2] = (short)f2bf(wv2 - __uint_as_float(h0 << 16));
        h0 = f2bf(wv3); ahi[3] = (short)h0; alo[3] = (short)f2bf(wv3 - __uint_as_float(h0 << 16));
        h0 = f2bf(wv4); ahi[4] = (short)h0; alo[4] = (short)f2bf(wv4 - __uint_as_float(h0 << 16));
        h0 = f2bf(wv5); ahi[5] = (short)h0; alo[5] = (short)f2bf(wv5 - __uint_as_float(h0 << 16));
        h0 = f2bf(wv6); ahi[6] = (short)h0; alo[6] = (short)f2bf(wv6 - __uint_as_float(h0 << 16));
        h0 = f2bf(wv7); ahi[7] = (short)h0; alo[7] = (short)f2bf(wv7 - __uint_as_float(h0 << 16));
#pragma unroll
        for (int c = 0; c < 8; c++) {
            acc[c] = __builtin_amdgcn_mfma_f32_16x16x32_bf16(ahi, bf[c], acc[c], 0, 0, 0);
            acc[c] = __builtin_amdgcn_mfma_f32_16x16x32_bf16(alo, bf[c], acc[c], 0, 0, 0);
        }
    }
    float* pbase = part + (size_t)kc * (H_DIM * B_DIM)
                 + (size_t)(mt * 64 + w * 16 + (l >> 4) * 4) * B_DIM + lr;
#pragma unroll
    for (int c = 0; c < 8; c++)
#pragma unroll
        for (int r = 0; r < 4; r++)
            pbase[(size_t)r * B_DIM + c * 16] = acc[c][r];
}

// ---------- reduce split-K partials + bias + relu -> h1[b][j] ----------
__global__ void k_reduce1(const float* __restrict__ part, const float* __restrict__ b1,
                          float* __restrict__ h1) {
    int idx = blockIdx.x * 256 + threadIdx.x;  // 0..65535 (j*128+b)
    int j = idx >> 7;
    int b = idx & 127;
    float s = b1[j];
#pragma unroll
    for (int c = 0; c < SPLITK; c++) s += part[c * (H_DIM * B_DIM) + idx];
    h1[b * H_DIM + j] = fmaxf(s, 0.f);   // transposed write -> [b][j]
}

// ---------- GEMM2 (K-parallel): one wave per (b, 8 hidden units) ----------
__global__ void __launch_bounds__(256) k_gemm2(const float* __restrict__ W2,
                                               const float* __restrict__ b2,
                                               const float* __restrict__ h1,
                                               float* __restrict__ h2) {
    int w = blockIdx.x * 4 + (threadIdx.x >> 6);   // wave 0..8191
    int l = threadIdx.x & 63;
    int b = w >> 6;            // 0..127
    int j0 = (w & 63) * 8;     // 0..511 step 8
    const float* hb = h1 + (size_t)b * H_DIM;
    float hv[8];
#pragma unroll
    for (int k = 0; k < 8; k++) hv[k] = hb[k * 64 + l];
    float outv = 0.f;
#pragma unroll
    for (int jj = 0; jj < 8; jj++) {
        const float* wrow = W2 + (size_t)(j0 + jj) * H_DIM;
        float a = 0.f;
#pragma unroll
        for (int k = 0; k < 8; k++) a = fmaf(wrow[k * 64 + l], hv[k], a);
#pragma unroll
        for (int o = 1; o < 64; o <<= 1) a += __shfl_xor(a, o);
        if (l == jj) outv = a;
    }
    if (l < 8) h2[(size_t)b * H_DIM + j0 + l] = fmaxf(outv + b2[j0 + l], 0.f);
}

// ---------- GEMM3 (K-parallel): one wave per batch row, all 10 classes ----------
__global__ void __launch_bounds__(256) k_gemm3(const float* __restrict__ Wfc,
                                               const float* __restrict__ bfc,
                                               const float* __restrict__ h2,
                                               float* __restrict__ out) {
    int b = blockIdx.x * 4 + (threadIdx.x >> 6);   // 0..127
    int l = threadIdx.x & 63;
    const float* hb = h2 + (size_t)b * H_DIM;
    float hv[8];
#pragma unroll
    for (int k = 0; k < 8; k++) hv[k] = hb[k * 64 + l];
    float outv = 0.f;
#pragma unroll
    for (int c = 0; c < C_DIM; c++) {
        const float* wrow = Wfc + (size_t)c * H_DIM;
        float a = 0.f;
#pragma unroll
        for (int k = 0; k < 8; k++) a = fmaf(wrow[k * 64 + l], hv[k], a);
#pragma unroll
        for (int o = 1; o < 64; o <<= 1) a += __shfl_xor(a, o);
        if (l == c) outv = a;
    }
    if (l < C_DIM) out[b * C_DIM + l] = outv + bfc[l];
}

extern "C" void kernel_launch(void* const* d_in, const int* in_sizes, int n_in,
                              void* d_out, int out_size, void* d_ws, size_t ws_size,
                              hipStream_t stream) {
    const float* x   = (const float*)d_in[0];
    const int*   ei  = (const int*)d_in[1];
    const float* ew  = (const float*)d_in[2];
    const float* W1  = (const float*)d_in[3];
    const float* b1  = (const float*)d_in[4];
    const float* W2  = (const float*)d_in[5];
    const float* b2  = (const float*)d_in[6];
    const float* Wfc = (const float*)d_in[7];
    const float* bfc = (const float*)d_in[8];
    float* out = (float*)d_out;

    const int* src = ei;
    const int* dst = ei + E_DIM;

    char* ws = (char*)d_ws;
    size_t off = 0;
    auto alloc = [&](size_t bytes) -> void* {
        void* p = ws + off;
        off = (off + bytes + 255) & ~(size_t)255;
        return p;
    };
    uint16_t* xTh = (uint16_t*)alloc((size_t)N_DIM * B_DIM * 2);       // 4 MB bf16 [n][b]
    float* hT     = (float*)alloc((size_t)N_DIM * B_DIM * 4);          // 8 MB f32 [n][b]
    int2*  packed = (int2*) alloc((size_t)E_DIM * 8);                  // 8 MB
    // scratch union (lifetimes disjoint, stream-ordered):
    //   [hist1..place2] : slab 8 MB + grp 256 KB
    //   [gemm1..reduce1]: part 16 MB
    size_t sort_bytes = (size_t)NWG * NWORD * 4 + (size_t)NGRP * NWORD * 4;
    size_t part_bytes = (size_t)SPLITK * H_DIM * B_DIM * 4;
    char* scratch = (char*)alloc(sort_bytes > part_bytes ? sort_bytes : part_bytes);
    float* h1     = (float*)alloc((size_t)H_DIM * B_DIM * 4);
    float* h2     = (float*)alloc((size_t)H_DIM * B_DIM * 4);
    int*   offs   = (int*)  alloc((size_t)(N_DIM + 1) * 4);
    float* dinv   = (float*)alloc((size_t)N_DIM * 4);
    uint16_t* hB  = (uint16_t*)alloc((size_t)B_DIM * N_DIM * 2);       // 4 MB bf16 [b][n]
    uint32_t* slab = (uint32_t*)scratch;
    uint32_t* grp  = (uint32_t*)(scratch + (size_t)NWG * NWORD * 4);
    float* part    = (float*)scratch;      // alias: live only gemm1..reduce1
    if (off > ws_size) return;

    k_transpose<<<dim3(N_DIM / 32, B_DIM / 32), dim3(32, 32), 0, stream>>>(x, xTh);
    k_hist1<<<NWG, 256, 0, stream>>>(dst, slab);
    k_scanA<<<NWORD * NGRP / 256, 256, 0, stream>>>(slab, grp);
    k_scanBC<<<1, 1024, 0, stream>>>(grp, offs);
    k_place2<<<NWG, 256, 0, stream>>>(src, dst, ew, slab, grp, offs, packed);
    k_deg<<<N_DIM / 4, 256, 0, stream>>>(offs, packed, dinv);
    k_diffuse<<<N_DIM / 2, 256, 0, stream>>>(xTh, offs, packed, dinv, hT);
    k_h2b<<<dim3(N_DIM / 32, B_DIM / 32), dim3(32, 32), 0, stream>>>(hT, hB);
    k_gemm1<<<dim3(SPLITK, H_DIM / 64), 256, 0, stream>>>(W1, hB, part);
    k_reduce1<<<(H_DIM * B_DIM) / 256, 256, 0, stream>>>(part, b1, h1);
    k_gemm2<<<(B_DIM * (H_DIM / 8)) / 4, 256, 0, stream>>>(W2, b2, h1, h2);
    k_gemm3<<<B_DIM / 4, 256, 0, stream>>>(Wfc, bfc, h2, out);
}

// Round 13
// 148.169 us; speedup vs baseline: 1.0203x; 1.0203x over previous
//
#include <hip/hip_runtime.h>
#include <hip/hip_bf16.h>
#include <stdint.h>

#define B_DIM 128
#define N_DIM 16384
#define E_DIM 1048576
#define H_DIM 512
#define C_DIM 10
#define NWG 256               // wgs for hist/place
#define CHUNK (E_DIM / NWG)   // 4096 edges per wg
#define NWORD (N_DIM / 2)     // 8192 packed uint words (2 bins each)
#define NGRP 8                // scan groups
#define WPG (NWG / NGRP)      // 32 wgs per group
#define SPLITK 64
#define KC (N_DIM / SPLITK)   // 256

typedef __attribute__((ext_vector_type(8))) short short8;   // 8 bf16 = 4 VGPRs
typedef __attribute__((ext_vector_type(4))) float f32x4;    // MFMA accumulator

// float -> bf16 round-to-nearest-even (finite inputs)
__device__ __forceinline__ uint32_t f2bf(float f) {
    uint32_t u = __float_as_uint(f);
    return (u + 0x7fffu + ((u >> 16) & 1u)) >> 16;
}

// ---------- transpose x (B,N) f32 -> xTh (N,B) bf16 (no scaling) ----------
__global__ void k_transpose(const float* __restrict__ x, uint16_t* __restrict__ xTh) {
    __shared__ float tile[32][33];
    int bx = blockIdx.x, by = blockIdx.y;
    int tx = threadIdx.x, ty = threadIdx.y;
    int n = bx * 32 + tx, b = by * 32 + ty;
    tile[ty][tx] = x[(size_t)b * N_DIM + n];
    __syncthreads();
    int n2 = bx * 32 + ty, b2 = by * 32 + tx;
    xTh[(size_t)n2 * B_DIM + b2] = (uint16_t)f2bf(tile[tx][ty]);
}

// ---------- per-wg LDS histogram of dst (2x16-bit packed), flush to slab ----------
__global__ void __launch_bounds__(256) k_hist1(const int* __restrict__ dst,
                                               uint32_t* __restrict__ slab) {
    __shared__ uint32_t lh[NWORD];   // 32 KB
    int w = blockIdx.x, t = threadIdx.x;
#pragma unroll
    for (int i = 0; i < NWORD / 256; i++) lh[i * 256 + t] = 0;
    __syncthreads();
#pragma unroll
    for (int i = 0; i < CHUNK / 256; i++) {
        int d = dst[w * CHUNK + i * 256 + t];
        atomicAdd(&lh[d >> 1], 1u << ((d & 1) << 4));
    }
    __syncthreads();
#pragma unroll
    for (int i = 0; i < NWORD / 256; i++)
        slab[(size_t)w * NWORD + i * 256 + t] = lh[i * 256 + t];
}

// ---------- within-group (32 wgs) in-place exclusive prefix; per-group totals ----------
__global__ void __launch_bounds__(256) k_scanA(uint32_t* __restrict__ slab,
                                               uint32_t* __restrict__ grp) {
    int b = blockIdx.x;                 // 0..255
    int g = b >> 5;                     // group 0..7
    int j = (b & 31) * 256 + threadIdx.x;  // word 0..8191
    uint32_t lo = 0, hi = 0;
    for (int w = g * WPG; w < (g + 1) * WPG; w++) {
        uint32_t c = slab[(size_t)w * NWORD + j];
        slab[(size_t)w * NWORD + j] = lo | (hi << 16);
        lo += c & 0xffffu;
        hi += c >> 16;
    }
    grp[(size_t)g * NWORD + j] = lo | (hi << 16);
}

// ---------- fused: cross-group exclusive prefix + global bin scan -> CSR offs ----------
__global__ void __launch_bounds__(1024) k_scanBC(uint32_t* __restrict__ grp,
                                                 int* __restrict__ offs) {
    __shared__ uint32_t part[1024];
    int t = threadIdx.x;
    uint32_t loc[16];
    uint32_t s = 0;
    int wbase = t * 8;
#pragma unroll
    for (int i = 0; i < 8; i++) {
        int j = wbase + i;
        uint32_t lo = 0, hi = 0;
#pragma unroll
        for (int g = 0; g < NGRP; g++) {
            uint32_t c = grp[(size_t)g * NWORD + j];
            grp[(size_t)g * NWORD + j] = lo | (hi << 16);
            lo += c & 0xffffu;
            hi += c >> 16;
        }
        loc[2 * i] = s;     s += lo;
        loc[2 * i + 1] = s; s += hi;
    }
    part[t] = s;
    __syncthreads();
    for (int off = 1; off < 1024; off <<= 1) {
        uint32_t v = (t >= off) ? part[t - off] : 0;
        __syncthreads();
        part[t] += v;
        __syncthreads();
    }
    uint32_t ex = (t == 0) ? 0 : part[t - 1];
#pragma unroll
    for (int i = 0; i < 16; i++) offs[t * 16 + i] = (int)(ex + loc[i]);
    if (t == 1023) offs[N_DIM] = (int)part[1023];
}

// ---------- atomic-free (global) placement: LDS cursor per wg ----------
__global__ void __launch_bounds__(256) k_place2(const int* __restrict__ src,
                                                const int* __restrict__ dst,
                                                const float* __restrict__ ew,
                                                const uint32_t* __restrict__ slab,
                                                const uint32_t* __restrict__ grp,
                                                const int* __restrict__ offs,
                                                int2* __restrict__ packed) {
    __shared__ uint32_t cur[N_DIM];   // 64 KB
    int w = blockIdx.x, t = threadIdx.x;
    int g = w >> 5;
#pragma unroll
    for (int i = 0; i < NWORD / 256; i++) {
        int j = i * 256 + t;
        uint32_t pv = slab[(size_t)w * NWORD + j];
        uint32_t gv = grp[(size_t)g * NWORD + j];
        int2 o = *(const int2*)&offs[2 * j];
        cur[2 * j]     = (uint32_t)o.x + (gv & 0xffffu) + (pv & 0xffffu);
        cur[2 * j + 1] = (uint32_t)o.y + (gv >> 16) + (pv >> 16);
    }
    __syncthreads();
#pragma unroll
    for (int i = 0; i < CHUNK / 256; i++) {
        int e = w * CHUNK + i * 256 + t;
        int s = src[e], d = dst[e];
        uint32_t pos = atomicAdd(&cur[d], 1u);   // LDS atomic
        packed[pos] = make_int2(s, __float_as_int(ew[e]));
    }
}

// ---------- weighted in-degree from sorted segments -> dinv (raw w in packed) ----------
__global__ void __launch_bounds__(256) k_deg(const int* __restrict__ offs,
                                             const int2* __restrict__ packed,
                                             float* __restrict__ dinv) {
    int d = blockIdx.x * 4 + (threadIdx.x >> 6);
    int lane = threadIdx.x & 63;
    int e0 = offs[d], e1 = offs[d + 1];
    float s = 0.f;
    for (int e = e0 + lane; e < e1; e += 64)
        s += __int_as_float(packed[e].y);
#pragma unroll
    for (int o = 32; o > 0; o >>= 1) s += __shfl_down(s, o);
    if (lane == 0) dinv[d] = rsqrtf(s + 1.0f);   // + self-loop weight 1; always > 0
}

// ---------- diffusion: single visit per node, all 128 cols, bf16 out ----------
// grid = N_DIM/4 blocks x 256 thr (4 waves = 4 nodes, one wave per node).
// 4 edge groups x 16 lanes x uint4 = 1 KB per gather instr, 4 edges/instr, full
// 128-col coverage -> packed+dinv read ONCE per edge (was 2x with slices), half
// the per-visit prologue exposure. 4 MB bf16 table is L2-resident per XCD.
// Per 64-edge tile: ONE coalesced packed load (prefetched a tile early, dinv[src]
// folded at staging), 16 unrolled {shfl-broadcast, gather, unpack, fma} steps.
// OOB lanes stage w=0 -> inert. Output written as bf16 [n][b] (same rounding the
// old h2b applied, so final hB is bit-identical).
__global__ void __launch_bounds__(256) k_diffuse(const uint16_t* __restrict__ xTh,
                                                 const int* __restrict__ offs,
                                                 const int2* __restrict__ packed,
                                                 const float* __restrict__ dinv,
                                                 uint16_t* __restrict__ hTb) {
    int d = blockIdx.x * 4 + (threadIdx.x >> 6);
    int lane = threadIdx.x & 63;
    int g = lane >> 4;                  // edge subgroup 0..3
    int colh = lane & 15;               // uint4 chunk within row (16 per row)
    const uint4* x4 = (const uint4*)xTh;
    float acc[8];
#pragma unroll
    for (int k = 0; k < 8; k++) acc[k] = 0.f;
    int e0 = offs[d], e1 = offs[d + 1];
    int el = e0 + lane;
    int2 p = (el < e1) ? packed[el] : make_int2(0, 0);
    p.y = __float_as_int(__int_as_float(p.y) * dinv[p.x]);   // w*dinv[src]; 0 stays 0
    for (int base = e0; base < e1; base += 64) {
        int2 pc = p;
        int en = base + 64 + lane;
        p = (en < e1) ? packed[en] : make_int2(0, 0);        // prefetch next tile
        p.y = __float_as_int(__int_as_float(p.y) * dinv[p.x]);
#pragma unroll
        for (int i = 0; i < 64; i += 4) {
            int idx = i + g;
            int sx = __shfl(pc.x, idx);
            float nm = __shfl(__int_as_float(pc.y), idx);
            uint4 xs = x4[(size_t)sx * 16 + colh];
            acc[0] = fmaf(nm, __uint_as_float(xs.x << 16), acc[0]);
            acc[1] = fmaf(nm, __uint_as_float(xs.x & 0xffff0000u), acc[1]);
            acc[2] = fmaf(nm, __uint_as_float(xs.y << 16), acc[2]);
            acc[3] = fmaf(nm, __uint_as_float(xs.y & 0xffff0000u), acc[3]);
            acc[4] = fmaf(nm, __uint_as_float(xs.z << 16), acc[4]);
            acc[5] = fmaf(nm, __uint_as_float(xs.z & 0xffff0000u), acc[5]);
            acc[6] = fmaf(nm, __uint_as_float(xs.w << 16), acc[6]);
            acc[7] = fmaf(nm, __uint_as_float(xs.w & 0xffff0000u), acc[7]);
        }
    }
#pragma unroll
    for (int off = 16; off <= 32; off <<= 1)
#pragma unroll
        for (int k = 0; k < 8; k++) acc[k] += __shfl_xor(acc[k], off);
    if (lane < 16) {
        float dv = dinv[d];
        uint4 sv = x4[(size_t)d * 16 + colh];   // self row (unscaled bf16)
        float o[8];
        o[0] = (acc[0] + dv * __uint_as_float(sv.x << 16)) * dv;
        o[1] = (acc[1] + dv * __uint_as_float(sv.x & 0xffff0000u)) * dv;
        o[2] = (acc[2] + dv * __uint_as_float(sv.y << 16)) * dv;
        o[3] = (acc[3] + dv * __uint_as_float(sv.y & 0xffff0000u)) * dv;
        o[4] = (acc[4] + dv * __uint_as_float(sv.z << 16)) * dv;
        o[5] = (acc[5] + dv * __uint_as_float(sv.z & 0xffff0000u)) * dv;
        o[6] = (acc[6] + dv * __uint_as_float(sv.w << 16)) * dv;
        o[7] = (acc[7] + dv * __uint_as_float(sv.w & 0xffff0000u)) * dv;
        uint4 r;
        r.x = f2bf(o[0]) | (f2bf(o[1]) << 16);
        r.y = f2bf(o[2]) | (f2bf(o[3]) << 16);
        r.z = f2bf(o[4]) | (f2bf(o[5]) << 16);
        r.w = f2bf(o[6]) | (f2bf(o[7]) << 16);
        ((uint4*)(hTb + (size_t)d * B_DIM))[colh] = r;
    }
}

// ---------- hTb bf16 [n][b] -> hB bf16 [b][n] (pure transpose) ----------
__global__ void k_h2b(const uint16_t* __restrict__ hTb, uint16_t* __restrict__ hB) {
    __shared__ uint16_t tile[32][34];   // +2 pad breaks bank aliasing
    int n0 = blockIdx.x * 32, b0 = blockIdx.y * 32;
    int tx = threadIdx.x, ty = threadIdx.y;
    tile[ty][tx] = hTb[(size_t)(n0 + ty) * B_DIM + b0 + tx];
    __syncthreads();
    hB[(size_t)(b0 + ty) * N_DIM + n0 + tx] = tile[tx][ty];
}

// ---------- GEMM1 (MFMA bf16, error-compensated W): W1 x h -> split-K partials ----
__global__ void __launch_bounds__(256) k_gemm1(const float* __restrict__ W1,
                                               const uint16_t* __restrict__ hB,
                                               float* __restrict__ part) {
    int kc = blockIdx.x;               // 0..SPLITK-1
    int mt = blockIdx.y;               // 0..7
    int t = threadIdx.x, w = t >> 6, l = t & 63;
    int lr = l & 15;
    int lk = (l >> 4) * 8;
    int row = mt * 64 + w * 16 + lr;   // W1 row for A-frag
    int k0 = kc * KC;
    f32x4 acc[8] = {};
    const float* wbase = W1 + (size_t)row * N_DIM + k0 + lk;
    const uint16_t* hbase = hB + k0 + lk;
#pragma unroll 2
    for (int ks = 0; ks < KC; ks += 32) {
        float4 wa = *(const float4*)(wbase + ks);
        float4 wb = *(const float4*)(wbase + ks + 4);
        short8 bf[8];
#pragma unroll
        for (int c = 0; c < 8; c++)
            bf[c] = *(const short8*)(hbase + (size_t)(c * 16 + lr) * N_DIM + ks);
        float wv0 = wa.x, wv1 = wa.y, wv2 = wa.z, wv3 = wa.w;
        float wv4 = wb.x, wv5 = wb.y, wv6 = wb.z, wv7 = wb.w;
        short8 ahi, alo;
        uint32_t h0;
        h0 = f2bf(wv0); ahi[0] = (short)h0; alo[0] = (short)f2bf(wv0 - __uint_as_float(h0 << 16));
        h0 = f2bf(wv1); ahi[1] = (short)h0; alo[1] = (short)f2bf(wv1 - __uint_as_float(h0 << 16));
        h0 = f2bf(wv2); ahi[2] = (short)h0; alo[2] = (short)f2bf(wv2 - __uint_as_float(h0 << 16));
        h0 = f2bf(wv3); ahi[3] = (short)h0; alo[3] = (short)f2bf(wv3 - __uint_as_float(h0 << 16));
        h0 = f2bf(wv4); ahi[4] = (short)h0; alo[4] = (short)f2bf(wv4 - __uint_as_float(h0 << 16));
        h0 = f2bf(wv5); ahi[5] = (short)h0; alo[5] = (short)f2bf(wv5 - __uint_as_float(h0 << 16));
        h0 = f2bf(wv6); ahi[6] = (short)h0; alo[6] = (short)f2bf(wv6 - __uint_as_float(h0 << 16));
        h0 = f2bf(wv7); ahi[7] = (short)h0; alo[7] = (short)f2bf(wv7 - __uint_as_float(h0 << 16));
#pragma unroll
        for (int c = 0; c < 8; c++) {
            acc[c] = __builtin_amdgcn_mfma_f32_16x16x32_bf16(ahi, bf[c], acc[c], 0, 0, 0);
            acc[c] = __builtin_amdgcn_mfma_f32_16x16x32_bf16(alo, bf[c], acc[c], 0, 0, 0);
        }
    }
    float* pbase = part + (size_t)kc * (H_DIM * B_DIM)
                 + (size_t)(mt * 64 + w * 16 + (l >> 4) * 4) * B_DIM + lr;
#pragma unroll
    for (int c = 0; c < 8; c++)
#pragma unroll
        for (int r = 0; r < 4; r++)
            pbase[(size_t)r * B_DIM + c * 16] = acc[c][r];
}

// ---------- reduce split-K partials + bias + relu -> h1[b][j] ----------
__global__ void k_reduce1(const float* __restrict__ part, const float* __restrict__ b1,
                          float* __restrict__ h1) {
    int idx = blockIdx.x * 256 + threadIdx.x;  // 0..65535 (j*128+b)
    int j = idx >> 7;
    int b = idx & 127;
    float s = b1[j];
#pragma unroll
    for (int c = 0; c < SPLITK; c++) s += part[c * (H_DIM * B_DIM) + idx];
    h1[b * H_DIM + j] = fmaxf(s, 0.f);   // transposed write -> [b][j]
}

// ---------- GEMM2 (K-parallel): one wave per (b, 8 hidden units) ----------
__global__ void __launch_bounds__(256) k_gemm2(const float* __restrict__ W2,
                                               const float* __restrict__ b2,
                                               const float* __restrict__ h1,
                                               float* __restrict__ h2) {
    int w = blockIdx.x * 4 + (threadIdx.x >> 6);   // wave 0..8191
    int l = threadIdx.x & 63;
    int b = w >> 6;            // 0..127
    int j0 = (w & 63) * 8;     // 0..511 step 8
    const float* hb = h1 + (size_t)b * H_DIM;
    float hv[8];
#pragma unroll
    for (int k = 0; k < 8; k++) hv[k] = hb[k * 64 + l];
    float outv = 0.f;
#pragma unroll
    for (int jj = 0; jj < 8; jj++) {
        const float* wrow = W2 + (size_t)(j0 + jj) * H_DIM;
        float a = 0.f;
#pragma unroll
        for (int k = 0; k < 8; k++) a = fmaf(wrow[k * 64 + l], hv[k], a);
#pragma unroll
        for (int o = 1; o < 64; o <<= 1) a += __shfl_xor(a, o);
        if (l == jj) outv = a;
    }
    if (l < 8) h2[(size_t)b * H_DIM + j0 + l] = fmaxf(outv + b2[j0 + l], 0.f);
}

// ---------- GEMM3 (K-parallel): one wave per batch row, all 10 classes ----------
__global__ void __launch_bounds__(256) k_gemm3(const float* __restrict__ Wfc,
                                               const float* __restrict__ bfc,
                                               const float* __restrict__ h2,
                                               float* __restrict__ out) {
    int b = blockIdx.x * 4 + (threadIdx.x >> 6);   // 0..127
    int l = threadIdx.x & 63;
    const float* hb = h2 + (size_t)b * H_DIM;
    float hv[8];
#pragma unroll
    for (int k = 0; k < 8; k++) hv[k] = hb[k * 64 + l];
    float outv = 0.f;
#pragma unroll
    for (int c = 0; c < C_DIM; c++) {
        const float* wrow = Wfc + (size_t)c * H_DIM;
        float a = 0.f;
#pragma unroll
        for (int k = 0; k < 8; k++) a = fmaf(wrow[k * 64 + l], hv[k], a);
#pragma unroll
        for (int o = 1; o < 64; o <<= 1) a += __shfl_xor(a, o);
        if (l == c) outv = a;
    }
    if (l < C_DIM) out[b * C_DIM + l] = outv + bfc[l];
}

extern "C" void kernel_launch(void* const* d_in, const int* in_sizes, int n_in,
                              void* d_out, int out_size, void* d_ws, size_t ws_size,
                              hipStream_t stream) {
    const float* x   = (const float*)d_in[0];
    const int*   ei  = (const int*)d_in[1];
    const float* ew  = (const float*)d_in[2];
    const float* W1  = (const float*)d_in[3];
    const float* b1  = (const float*)d_in[4];
    const float* W2  = (const float*)d_in[5];
    const float* b2  = (const float*)d_in[6];
    const float* Wfc = (const float*)d_in[7];
    const float* bfc = (const float*)d_in[8];
    float* out = (float*)d_out;

    const int* src = ei;
    const int* dst = ei + E_DIM;

    char* ws = (char*)d_ws;
    size_t off = 0;
    auto alloc = [&](size_t bytes) -> void* {
        void* p = ws + off;
        off = (off + bytes + 255) & ~(size_t)255;
        return p;
    };
    uint16_t* xTh = (uint16_t*)alloc((size_t)N_DIM * B_DIM * 2);       // 4 MB bf16 [n][b]
    uint16_t* hTb = (uint16_t*)alloc((size_t)N_DIM * B_DIM * 2);       // 4 MB bf16 [n][b]
    int2*  packed = (int2*) alloc((size_t)E_DIM * 8);                  // 8 MB
    // scratch union (lifetimes disjoint, stream-ordered):
    //   [hist1..place2] : slab 8 MB + grp 256 KB
    //   [gemm1..reduce1]: part 16 MB
    size_t sort_bytes = (size_t)NWG * NWORD * 4 + (size_t)NGRP * NWORD * 4;
    size_t part_bytes = (size_t)SPLITK * H_DIM * B_DIM * 4;
    char* scratch = (char*)alloc(sort_bytes > part_bytes ? sort_bytes : part_bytes);
    float* h1     = (float*)alloc((size_t)H_DIM * B_DIM * 4);
    float* h2     = (float*)alloc((size_t)H_DIM * B_DIM * 4);
    int*   offs   = (int*)  alloc((size_t)(N_DIM + 1) * 4);
    float* dinv   = (float*)alloc((size_t)N_DIM * 4);
    uint16_t* hB  = (uint16_t*)alloc((size_t)B_DIM * N_DIM * 2);       // 4 MB bf16 [b][n]
    uint32_t* slab = (uint32_t*)scratch;
    uint32_t* grp  = (uint32_t*)(scratch + (size_t)NWG * NWORD * 4);
    float* part    = (float*)scratch;      // alias: live only gemm1..reduce1
    if (off > ws_size) return;

    k_transpose<<<dim3(N_DIM / 32, B_DIM / 32), dim3(32, 32), 0, stream>>>(x, xTh);
    k_hist1<<<NWG, 256, 0, stream>>>(dst, slab);
    k_scanA<<<NWORD * NGRP / 256, 256, 0, stream>>>(slab, grp);
    k_scanBC<<<1, 1024, 0, stream>>>(grp, offs);
    k_place2<<<NWG, 256, 0, stream>>>(src, dst, ew, slab, grp, offs, packed);
    k_deg<<<N_DIM / 4, 256, 0, stream>>>(offs, packed, dinv);
    k_diffuse<<<N_DIM / 4, 256, 0, stream>>>(xTh, offs, packed, dinv, hTb);
    k_h2b<<<dim3(N_DIM / 32, B_DIM / 32), dim3(32, 32), 0, stream>>>(hTb, hB);
    k_gemm1<<<dim3(SPLITK, H_DIM / 64), 256, 0, stream>>>(W1, hB, part);
    k_reduce1<<<(H_DIM * B_DIM) / 256, 256, 0, stream>>>(part, b1, h1);
    k_gemm2<<<(B_DIM * (H_DIM / 8)) / 4, 256, 0, stream>>>(W2, b2, h1, h2);
    k_gemm3<<<B_DIM / 4, 256, 0, stream>>>(Wfc, bfc, h2, out);
}